// Round 13
// baseline (459.150 us; speedup 1.0000x reference)
//
#include <hip/hip_runtime.h>
#include <hip/hip_bf16.h>
#include <math.h>

// Problem constants (fixed by the reference)
#define NN 50000
#define NE 800000
#define NPAD 50048
#define NTILES 3125   // NN/16 exactly — tail-free row tiles
#define NB_SCAN 196   // ceil(NN/256)

typedef unsigned short u16;
typedef unsigned int u32;
typedef __attribute__((ext_vector_type(8))) short short8;   // 8 bf16 (MFMA A/B frag)
typedef __attribute__((ext_vector_type(4))) float float4v;  // MFMA C/D frag

__device__ __forceinline__ float us2f(u16 u) { return __uint_as_float(((unsigned)u) << 16); }
__device__ __forceinline__ float blo(u32 u) { return __uint_as_float(u << 16); }
__device__ __forceinline__ float bhi(u32 u) { return __uint_as_float(u & 0xffff0000u); }
__device__ __forceinline__ u16 f2us(float f) {   // fp32 -> bf16 RNE
    unsigned x = __float_as_uint(f);
    return (u16)((x + 0x7FFFu + ((x >> 16) & 1u)) >> 16);
}
// tanh-gelu via sigmoid identity: 0.5*(1+tanh(u)) = sigmoid(2u)
__device__ __forceinline__ float gelu_f(float x) {
    float p = x * x;
    float t = x * fmaf(p, 0.0713548162726f, 1.5957691216057308f);  // 2u
    float e = __expf(-t);
    return x * __builtin_amdgcn_rcpf(1.0f + e);
}
// intra-wave LDS ordering fence (wave-private LDS; no cross-wave barriers)
__device__ __forceinline__ void lds_fence() {
    asm volatile("s_waitcnt lgkmcnt(0)" ::: "memory");
}

__device__ __forceinline__ float4v mfma4b(short8 a0, short8 a1, short8 a2, short8 a3,
                                          const short8* B) {
    float4v acc = {0.f, 0.f, 0.f, 0.f};
    acc = __builtin_amdgcn_mfma_f32_16x16x32_bf16(a0, B[0], acc, 0, 0, 0);
    acc = __builtin_amdgcn_mfma_f32_16x16x32_bf16(a1, B[1], acc, 0, 0, 0);
    acc = __builtin_amdgcn_mfma_f32_16x16x32_bf16(a2, B[2], acc, 0, 0, 0);
    acc = __builtin_amdgcn_mfma_f32_16x16x32_bf16(a3, B[3], acc, 0, 0, 0);
    return acc;
}

// ---------------- CSR build ----------------

__global__ void k_hist(const int* __restrict__ dstv, int* __restrict__ deg) {
    int e = blockIdx.x * blockDim.x + threadIdx.x;
    if (e < NE) atomicAdd(&deg[dstv[e]], 1);
}

__global__ __launch_bounds__(256) void k_scan1(const int* __restrict__ deg,
                                               int* __restrict__ rowstart,
                                               int* __restrict__ bsum) {
    __shared__ int wtot[4];
    int i = blockIdx.x * 256 + threadIdx.x;
    int lane = threadIdx.x & 63, w = threadIdx.x >> 6;
    int v = (i < NN) ? deg[i] : 0;
    int incl = v;
#pragma unroll
    for (int d = 1; d < 64; d <<= 1) {
        int tv = __shfl_up(incl, d);
        if (lane >= d) incl += tv;
    }
    if (lane == 63) wtot[w] = incl;
    __syncthreads();
    if (threadIdx.x == 0) {
        int s = 0;
#pragma unroll
        for (int j = 0; j < 4; ++j) { int t = wtot[j]; wtot[j] = s; s += t; }
        bsum[blockIdx.x] = s;
    }
    __syncthreads();
    if (i < NN) rowstart[i] = incl - v + wtot[w];
}

__global__ __launch_bounds__(256) void k_scan2(int* __restrict__ bsum) {
    __shared__ int wtot[4];
    int t = threadIdx.x;
    int lane = t & 63, w = t >> 6;
    int v = (t < NB_SCAN) ? bsum[t] : 0;
    int incl = v;
#pragma unroll
    for (int d = 1; d < 64; d <<= 1) {
        int tv = __shfl_up(incl, d);
        if (lane >= d) incl += tv;
    }
    if (lane == 63) wtot[w] = incl;
    __syncthreads();
    if (t == 0) {
        int s = 0;
#pragma unroll
        for (int j = 0; j < 4; ++j) { int tt = wtot[j]; wtot[j] = s; s += tt; }
    }
    __syncthreads();
    if (t < NB_SCAN) bsum[t] = incl - v + wtot[w];
}

__global__ void k_scan3(const int* __restrict__ bsum, int* __restrict__ rowstart,
                        int* __restrict__ cursor) {
    int i = blockIdx.x * 256 + threadIdx.x;
    if (i < NN) {
        int v = rowstart[i] + bsum[blockIdx.x];
        rowstart[i] = v;
        cursor[i] = v;
    }
    if (i == 0) rowstart[NN] = NE;
}

__global__ void k_scatter(const int* __restrict__ srcv, const int* __restrict__ dstv,
                          const float* __restrict__ eattr, int* __restrict__ cursor,
                          int4* __restrict__ rec) {
    int e = blockIdx.x * blockDim.x + threadIdx.x;
    if (e >= NE) return;
    int dst = dstv[e];
    int pos = atomicAdd(&cursor[dst], 1);
    int4 r;
    r.x = srcv[e];
    r.y = __float_as_int(eattr[e * 3 + 0]);
    r.z = __float_as_int(eattr[e * 3 + 1]);
    r.w = __float_as_int(eattr[e * 3 + 2]);
    rec[pos] = r;
}

// ---------------- weight fp32 -> bf16, permuted into B-frag order ----------------
// WP u16 layout: tile*2048 + q*512 + l*8 + j <=> W[tile*16+(l&15)][q*32+(l>>4)*8+j]

struct CvtEnt { const float* s; u16* d; int n; };
struct CvtTab { CvtEnt e[14]; };
__global__ void k_cvt_w(CvtTab tab) {
    CvtEnt E = tab.e[blockIdx.x >> 3];
    int chunk = blockIdx.x & 7;
    int per = E.n >> 3;
    int lo = chunk * per, hi = lo + per;
    for (int o = lo + threadIdx.x; o < hi; o += blockDim.x) {
        int tile = o >> 11;
        int q = (o >> 9) & 3;
        int l = (o >> 3) & 63;
        int j = o & 7;
        int row = tile * 16 + (l & 15);
        int col = q * 32 + (l >> 4) * 8 + j;
        E.d[o] = f2us(E.s[row * 128 + col]);
    }
}

// padded We tables: WeP[c] = {We[c][0], We[c][1], We[c][2], 0}
__global__ void k_prep_we(const float* __restrict__ We1, const float* __restrict__ We2,
                          float4* __restrict__ WeP1, float4* __restrict__ WeP2) {
    int t = threadIdx.x;
    if (t < 128) {
        WeP1[t] = make_float4(We1[t * 3], We1[t * 3 + 1], We1[t * 3 + 2], 0.f);
    } else {
        int c = t - 128;
        WeP2[c] = make_float4(We2[c * 3], We2[c * 3 + 1], We2[c * 3 + 2], 0.f);
    }
}

// =============== weight-stationary streaming GEMM kernels ===============
// 1-wave blocks, wave-private LDS, B-frags resident in VGPRs, grid-stride rows.

__device__ __forceinline__ void store128(const u16* buf, u16* dst, int r0w, int coff, int l) {
#pragma unroll
    for (int it = 0; it < 4; ++it) {
        int j = it * 64 + l;
        int row = j >> 4, col = (j & 15) * 8;
        *(uint4*)(dst + (size_t)(r0w + row) * 512 + coff + col) = *(const uint4*)&buf[row * 136 + col];
    }
}

// g precompute: q tile (16x128 bf16, plain layout) in buf; lane l computes
// g[row=m][head=kb][j] = sum_d q[row][kb*32+d] * WeP[kb*32+d].j
__device__ __forceinline__ void compute_g(const u16* buf, const float4* __restrict__ WeP,
                                          float4* __restrict__ G, int r0w, int m, int kb) {
    const u16* qr = buf + m * 136 + kb * 32;
    const float4* wp = WeP + kb * 32;
    float g0 = 0.f, g1 = 0.f, g2 = 0.f;
#pragma unroll
    for (int b = 0; b < 4; ++b) {
        short8 qv = *(const short8*)(qr + b * 8);
        const u16* qq = (const u16*)&qv;
#pragma unroll
        for (int d = 0; d < 8; ++d) {
            float qvf = us2f(qq[d]);
            float4 wv = wp[b * 8 + d];
            g0 = fmaf(qvf, wv.x, g0);
            g1 = fmaf(qvf, wv.y, g1);
            g2 = fmaf(qvf, wv.z, g2);
        }
    }
    G[(size_t)(r0w + m) * 4 + kb] = make_float4(g0, g1, g2, 0.f);
}

__device__ __forceinline__ void load_a32(const float* __restrict__ A, int row, int kb,
                                         short8& a0, short8& a1, short8& a2, short8& a3) {
    const float* ap = A + (size_t)row * 128;
    short8* dsts[4] = {&a0, &a1, &a2, &a3};
#pragma unroll
    for (int i = 0; i < 4; ++i) {
        const float* p = ap + (kb + i * 4) * 8;
        float4 f0 = *(const float4*)p;
        float4 f1 = *(const float4*)(p + 4);
        short8 r;
        r[0]=(short)f2us(f0.x); r[1]=(short)f2us(f0.y); r[2]=(short)f2us(f0.z); r[3]=(short)f2us(f0.w);
        r[4]=(short)f2us(f1.x); r[5]=(short)f2us(f1.y); r[6]=(short)f2us(f1.z); r[7]=(short)f2us(f1.w);
        *dsts[i] = r;
    }
}
__device__ __forceinline__ void load_a16(const u16* __restrict__ A, int row, int kb,
                                         short8& a0, short8& a1, short8& a2, short8& a3) {
    const short8* arow = (const short8*)(A + (size_t)row * 128);
    a0 = arow[kb]; a1 = arow[kb + 4]; a2 = arow[kb + 8]; a3 = arow[kb + 12];
}

// plain-section kernel. grid.y selects W tile base (y*sec_tile_mul) and column
// offset (ocol + y*sec_coff_mul). GCOMP only runs for y==0.
template <bool A32, int NT, bool GCOMP, bool GELU_, bool RES, bool F32OUT>
__global__ __launch_bounds__(64, 2) void k_gs(const void* __restrict__ Ain,
                                              const u16* __restrict__ W,
                                              const float* __restrict__ bias,
                                              const u16* __restrict__ res,
                                              void* __restrict__ outp,
                                              int ostride, int ocol,
                                              int sec_tile_mul, int sec_coff_mul,
                                              const float4* __restrict__ WeP,
                                              float4* __restrict__ G) {
    __shared__ u16 my[16 * 136];
    int l = threadIdx.x;
    int m = l & 15, kb = l >> 4;
    const u16* Wsec = W + (size_t)blockIdx.y * sec_tile_mul * 2048;
    int coff = ocol + blockIdx.y * sec_coff_mul;
    bool do_g = GCOMP && (blockIdx.y == 0);

    short8 B[NT][4];
#pragma unroll
    for (int t = 0; t < NT; ++t) {
        const short8* wp = (const short8*)Wsec + (size_t)t * 256 + l;
        B[t][0] = wp[0]; B[t][1] = wp[64]; B[t][2] = wp[128]; B[t][3] = wp[192];
    }
    float bv[NT];
    if (GELU_) {
#pragma unroll
        for (int t = 0; t < NT; ++t) bv[t] = bias[t * 16 + m];
    }

    for (int rt = blockIdx.x; rt < NTILES; rt += gridDim.x) {
        int r0w = rt * 16;
        short8 a0, a1, a2, a3;
        if (A32) load_a32((const float*)Ain, r0w + m, kb, a0, a1, a2, a3);
        else     load_a16((const u16*)Ain, r0w + m, kb, a0, a1, a2, a3);
#pragma unroll
        for (int tt = 0; tt < NT; ++tt) {
            float4v acc = mfma4b(a0, a1, a2, a3, B[tt]);
#pragma unroll
            for (int r = 0; r < 4; ++r) {
                float v = acc[r];
                if (GELU_) v = gelu_f(v + bv[tt]);
                my[(kb * 4 + r) * 136 + tt * 16 + m] = f2us(v);
            }
        }
        lds_fence();
        if (do_g) compute_g(my, WeP, G, r0w, m, kb);
        if (F32OUT) {
#pragma unroll
            for (int it = 0; it < 2; ++it) {
                int j = it * 64 + l;
                int row = j >> 3, col = (j & 7) * 8;
                uint4 pk = *(const uint4*)&my[row * 136 + col];
                const u16* pv = (const u16*)&pk;
                float* po = (float*)outp + (size_t)(r0w + row) * 64 + col;
                float4 o0 = {us2f(pv[0]), us2f(pv[1]), us2f(pv[2]), us2f(pv[3])};
                float4 o1 = {us2f(pv[4]), us2f(pv[5]), us2f(pv[6]), us2f(pv[7])};
                *(float4*)po = o0;
                *(float4*)(po + 4) = o1;
            }
        } else {
#pragma unroll
            for (int it = 0; it < 4; ++it) {
                int j = it * 64 + l;
                int row = j >> 4, col = (j & 15) * 8;
                uint4 pk = *(const uint4*)&my[row * 136 + col];
                if (RES) {
                    uint4 rk = *(const uint4*)(res + (size_t)(r0w + row) * 128 + col);
                    u16* po = (u16*)&pk;
                    const u16* pr = (const u16*)&rk;
#pragma unroll
                    for (int j2 = 0; j2 < 8; ++j2) po[j2] = f2us(us2f(po[j2]) + us2f(pr[j2]));
                }
                *(uint4*)((u16*)outp + (size_t)(r0w + row) * ostride + coff + col) = pk;
            }
        }
        lds_fence();
    }
}

// kv-section kernel: grid.y=0 -> k tiles 8..11 + v 16..19, coff 128;
//                    grid.y=1 -> k tiles 12..15 + v 20..23, coff 256.
// kv stage layout: col c -> k at (c>>2)*8+(c&3), v at +4 (conv reads 32B/lane).
template <bool A32>
__global__ __launch_bounds__(64, 2) void k_gs_kv(const void* __restrict__ Ain,
                                                 const u16* __restrict__ W,
                                                 u16* __restrict__ QKVS) {
    __shared__ u16 my[16 * 136];
    int l = threadIdx.x;
    int m = l & 15, kb = l >> 4;
    int kbase = 8 + 4 * blockIdx.y;
    int vbase = 16 + 4 * blockIdx.y;
    int coff = 128 + 128 * blockIdx.y;

    short8 Bk[4][4], Bv[4][4];
#pragma unroll
    for (int t = 0; t < 4; ++t) {
        const short8* wk = (const short8*)W + (size_t)(kbase + t) * 256 + l;
        Bk[t][0] = wk[0]; Bk[t][1] = wk[64]; Bk[t][2] = wk[128]; Bk[t][3] = wk[192];
        const short8* wv = (const short8*)W + (size_t)(vbase + t) * 256 + l;
        Bv[t][0] = wv[0]; Bv[t][1] = wv[64]; Bv[t][2] = wv[128]; Bv[t][3] = wv[192];
    }

    for (int rt = blockIdx.x; rt < NTILES; rt += gridDim.x) {
        int r0w = rt * 16;
        short8 a0, a1, a2, a3;
        if (A32) load_a32((const float*)Ain, r0w + m, kb, a0, a1, a2, a3);
        else     load_a16((const u16*)Ain, r0w + m, kb, a0, a1, a2, a3);
#pragma unroll
        for (int tt = 0; tt < 4; ++tt) {
            float4v acc = mfma4b(a0, a1, a2, a3, Bk[tt]);
            int c = tt * 32 + 8 * (m >> 2) + (m & 3);
#pragma unroll
            for (int r = 0; r < 4; ++r) my[(kb * 4 + r) * 136 + c] = f2us(acc[r]);
        }
#pragma unroll
        for (int tt = 0; tt < 4; ++tt) {
            float4v acc = mfma4b(a0, a1, a2, a3, Bv[tt]);
            int c = tt * 32 + 8 * (m >> 2) + (m & 3) + 4;
#pragma unroll
            for (int r = 0; r < 4; ++r) my[(kb * 4 + r) * 136 + c] = f2us(acc[r]);
        }
        lds_fence();
        store128(my, QKVS, r0w, coff, l);
        lds_fence();
    }
}

// ---------------- TransformerConv: 4 edges/wave, 8 cols/lane, pipelined gather ----------------

__global__ __launch_bounds__(256) void k_conv(const int* __restrict__ rowstart,
                                              const int4* __restrict__ rec,
                                              const u16* __restrict__ qkvs,
                                              const float4* __restrict__ WeP,
                                              const float4* __restrict__ G,
                                              u16* __restrict__ out) {
    int n = blockIdx.x * 4 + (threadIdx.x >> 6);
    int l = threadIdx.x & 63;
    int quarter = l >> 4;
    int li = l & 15;
    int c0 = li * 8;
    const u16* qrow = qkvs + (size_t)n * 512;
    uint4 qu = *(const uint4*)(qrow + c0);
    const float SC = 0.17677669529663687f;
    float q0 = blo(qu.x) * SC, q1 = bhi(qu.x) * SC, q2 = blo(qu.y) * SC, q3 = bhi(qu.y) * SC;
    float q4 = blo(qu.z) * SC, q5 = bhi(qu.z) * SC, q6 = blo(qu.w) * SC, q7 = bhi(qu.w) * SC;
    float4 gg = G[(size_t)n * 4 + (li >> 2)];
    float g0 = gg.x * SC, g1 = gg.y * SC, g2 = gg.z * SC;

    int e0 = rowstart[n], e1 = rowstart[n + 1];
    int deg = e1 - e0;
    float ss = 0.f, S0 = 0.f, S1 = 0.f, S2 = 0.f;
    float o0 = 0.f, o1 = 0.f, o2 = 0.f, o3 = 0.f, o4 = 0.f, o5 = 0.f, o6 = 0.f, o7 = 0.f;

    if (deg > 0) {
        int iters = (deg + 3) >> 2;
        int eb = e0 + quarter;
        int elast = e1 - 1;
        int4 r0 = rec[min(eb, elast)];
        int4 r1 = rec[min(eb + 4, elast)];
        const u16* kvB = qkvs + 128 + (size_t)li * 16;
        uint4 kA = *(const uint4*)(kvB + (size_t)r0.x * 512);
        uint4 kB = *(const uint4*)(kvB + (size_t)r0.x * 512 + 8);
        for (int i = 0; i < iters; ++i) {
            int4 r2 = rec[min(eb + 4 * (i + 2), elast)];
            const u16* kp = kvB + (size_t)r1.x * 512;
            uint4 nA = *(const uint4*)(kp);
            uint4 nB = *(const uint4*)(kp + 8);
            float part = q0 * blo(kA.x) + q1 * bhi(kA.x) + q2 * blo(kA.y) + q3 * bhi(kA.y)
                       + q4 * blo(kB.x) + q5 * bhi(kB.x) + q6 * blo(kB.y) + q7 * bhi(kB.y);
            part += __shfl_xor(part, 1);
            part += __shfl_xor(part, 2);
            float ea0 = __int_as_float(r0.y), ea1 = __int_as_float(r0.z), ea2 = __int_as_float(r0.w);
            float alpha = fmaf(ea2, g2, fmaf(ea1, g1, fmaf(ea0, g0, part)));
            float p = __expf(fminf(alpha, 80.f));
            p = (eb + 4 * i < e1) ? p : 0.f;
            o0 = fmaf(p, blo(kA.z), o0);
            o1 = fmaf(p, bhi(kA.z), o1);
            o2 = fmaf(p, blo(kA.w), o2);
            o3 = fmaf(p, bhi(kA.w), o3);
            o4 = fmaf(p, blo(kB.z), o4);
            o5 = fmaf(p, bhi(kB.z), o5);
            o6 = fmaf(p, blo(kB.w), o6);
            o7 = fmaf(p, bhi(kB.w), o7);
            ss += p;
            S0 = fmaf(p, ea0, S0);
            S1 = fmaf(p, ea1, S1);
            S2 = fmaf(p, ea2, S2);
            r0 = r1; r1 = r2; kA = nA; kB = nB;
        }
    }
    o0 += __shfl_xor(o0, 16); o1 += __shfl_xor(o1, 16); o2 += __shfl_xor(o2, 16); o3 += __shfl_xor(o3, 16);
    o4 += __shfl_xor(o4, 16); o5 += __shfl_xor(o5, 16); o6 += __shfl_xor(o6, 16); o7 += __shfl_xor(o7, 16);
    ss += __shfl_xor(ss, 16); S0 += __shfl_xor(S0, 16); S1 += __shfl_xor(S1, 16); S2 += __shfl_xor(S2, 16);
    o0 += __shfl_xor(o0, 32); o1 += __shfl_xor(o1, 32); o2 += __shfl_xor(o2, 32); o3 += __shfl_xor(o3, 32);
    o4 += __shfl_xor(o4, 32); o5 += __shfl_xor(o5, 32); o6 += __shfl_xor(o6, 32); o7 += __shfl_xor(o7, 32);
    ss += __shfl_xor(ss, 32); S0 += __shfl_xor(S0, 32); S1 += __shfl_xor(S1, 32); S2 += __shfl_xor(S2, 32);

    if (quarter == 0) {
        float inv = __builtin_amdgcn_rcpf(fmaxf(ss, 1e-16f));
        float4 w0 = WeP[c0 + 0], w1 = WeP[c0 + 1], w2 = WeP[c0 + 2], w3 = WeP[c0 + 3];
        float4 w4 = WeP[c0 + 4], w5 = WeP[c0 + 5], w6 = WeP[c0 + 6], w7 = WeP[c0 + 7];
        o0 += w0.x * S0 + w0.y * S1 + w0.z * S2;
        o1 += w1.x * S0 + w1.y * S1 + w1.z * S2;
        o2 += w2.x * S0 + w2.y * S1 + w2.z * S2;
        o3 += w3.x * S0 + w3.y * S1 + w3.z * S2;
        o4 += w4.x * S0 + w4.y * S1 + w4.z * S2;
        o5 += w5.x * S0 + w5.y * S1 + w5.z * S2;
        o6 += w6.x * S0 + w6.y * S1 + w6.z * S2;
        o7 += w7.x * S0 + w7.y * S1 + w7.z * S2;
        uint4 su = *(const uint4*)(qrow + 384 + c0);
        float r0v = fmaf(o0, inv, blo(su.x));
        float r1v = fmaf(o1, inv, bhi(su.x));
        float r2v = fmaf(o2, inv, blo(su.y));
        float r3v = fmaf(o3, inv, bhi(su.y));
        float r4v = fmaf(o4, inv, blo(su.z));
        float r5v = fmaf(o5, inv, bhi(su.z));
        float r6v = fmaf(o6, inv, blo(su.w));
        float r7v = fmaf(o7, inv, bhi(su.w));
        uint4 ou;
        ou.x = (u32)f2us(r0v) | ((u32)f2us(r1v) << 16);
        ou.y = (u32)f2us(r2v) | ((u32)f2us(r3v) << 16);
        ou.z = (u32)f2us(r4v) | ((u32)f2us(r5v) << 16);
        ou.w = (u32)f2us(r6v) | ((u32)f2us(r7v) << 16);
        *(uint4*)(out + (size_t)n * 128 + c0) = ou;
    }
}

// ---------------- launcher ----------------

extern "C" void kernel_launch(void* const* d_in, const int* in_sizes, int n_in,
                              void* d_out, int out_size, void* d_ws, size_t ws_size,
                              hipStream_t stream) {
    const float* x = (const float*)d_in[0];
    const int* ei = (const int*)d_in[1];
    const float* eattr = (const float*)d_in[2];
    const float* Wq1 = (const float*)d_in[3];
    const float* Wk1 = (const float*)d_in[4];
    const float* Wv1 = (const float*)d_in[5];
    const float* We1 = (const float*)d_in[6];
    const float* Ws1 = (const float*)d_in[7];
    const float* M1a = (const float*)d_in[8];
    const float* b1a = (const float*)d_in[9];
    const float* M1b = (const float*)d_in[10];
    const float* b1b = (const float*)d_in[11];
    const float* Wq2 = (const float*)d_in[12];
    const float* Wk2 = (const float*)d_in[13];
    const float* Wv2 = (const float*)d_in[14];
    const float* We2 = (const float*)d_in[15];
    const float* Ws2 = (const float*)d_in[16];
    const float* M2a = (const float*)d_in[17];
    const float* b2a = (const float*)d_in[18];
    const float* M2b = (const float*)d_in[19];
    const float* b2b = (const float*)d_in[20];
    const float* Wf1 = (const float*)d_in[21];
    const float* bf1 = (const float*)d_in[22];
    const float* Wf2 = (const float*)d_in[23];
    const float* bf2 = (const float*)d_in[24];

    char* ws = (char*)d_ws;
    size_t off = 0;
    auto alloc = [&](size_t bytes) -> void* {
        void* p = ws + off;
        off = (off + bytes + 255) & ~(size_t)255;
        return p;
    };
    int* deg = (int*)alloc((size_t)NN * 4);
    int* rowstart = (int*)alloc((size_t)(NN + 1) * 4);
    int* cursor = (int*)alloc((size_t)NN * 4);
    int* bsum = (int*)alloc((size_t)NB_SCAN * 4);
    int4* rec = (int4*)alloc((size_t)NE * 16);
    u16* QKVS = (u16*)alloc((size_t)NPAD * 512 * 2);
    u16* Ha = (u16*)alloc((size_t)NPAD * 128 * 2);
    u16* Hb = (u16*)alloc((size_t)NPAD * 128 * 2);
    u16* Tb = (u16*)alloc((size_t)NPAD * 128 * 2);
    float4* G = (float4*)alloc((size_t)NPAD * 4 * 16);
    float4* WeP1 = (float4*)alloc(128 * 16);
    float4* WeP2 = (float4*)alloc(128 * 16);
    // weight order: [Wq1 Wk1 Wv1 Ws1][Wq2 Wk2 Wv2 Ws2][M1a M1b][M2a M2b][Wf1 Wf2]
    u16* WB[14];
    const int wsz[14] = {16384, 16384, 16384, 16384, 16384, 16384, 16384,
                         16384, 16384, 16384, 16384, 16384, 16384, 8192};
    for (int i = 0; i < 14; ++i) WB[i] = (u16*)alloc((size_t)wsz[i] * 2);

    const int* srcv = ei;
    const int* dstv = ei + NE;

    // CSR build
    hipMemsetAsync(deg, 0, (size_t)NN * 4, stream);
    k_hist<<<(NE + 255) / 256, 256, 0, stream>>>(dstv, deg);
    k_scan1<<<NB_SCAN, 256, 0, stream>>>(deg, rowstart, bsum);
    k_scan2<<<1, 256, 0, stream>>>(bsum);
    k_scan3<<<NB_SCAN, 256, 0, stream>>>(bsum, rowstart, cursor);
    k_scatter<<<(NE + 255) / 256, 256, 0, stream>>>(srcv, dstv, eattr, cursor, rec);

    CvtTab tab;
    const float* wsrc[14] = {Wq1, Wk1, Wv1, Ws1, Wq2, Wk2, Wv2, Ws2,
                             M1a, M1b, M2a, M2b, Wf1, Wf2};
    for (int i = 0; i < 14; ++i) { tab.e[i].s = wsrc[i]; tab.e[i].d = WB[i]; tab.e[i].n = wsz[i]; }
    k_cvt_w<<<112, 256, 0, stream>>>(tab);
    k_prep_we<<<1, 256, 0, stream>>>(We1, We2, WeP1, WeP2);

    dim3 gqs(2048, 2);   // q+g / s sections
    dim3 gkv(2048, 2);   // kv-lo / kv-hi
    dim3 gm(2048);
    dim3 gconv(NN / 4);  // 12500

    // ----- layer 1 -----
    k_gs<true, 8, true, false, false, false><<<gqs, 64, 0, stream>>>(
        x, WB[0], nullptr, nullptr, QKVS, 512, 0, 24, 384, WeP1, G);
    k_gs_kv<true><<<gkv, 64, 0, stream>>>(x, WB[0], QKVS);
    k_conv<<<gconv, 256, 0, stream>>>(rowstart, rec, QKVS, WeP1, G, Ha);        // H1 = Ha
    // MLP1: Tb = gelu(Ha@M1a+b1a); Hb = gelu(Tb@M1b+b1b) + Ha  (= H2)
    k_gs<false, 8, false, true, false, false><<<gm, 64, 0, stream>>>(
        Ha, WB[8], b1a, nullptr, Tb, 128, 0, 0, 0, nullptr, nullptr);
    k_gs<false, 8, false, true, true, false><<<gm, 64, 0, stream>>>(
        Tb, WB[9], b1b, Ha, Hb, 128, 0, 0, 0, nullptr, nullptr);

    // ----- layer 2 -----
    k_gs<false, 8, true, false, false, false><<<gqs, 64, 0, stream>>>(
        Hb, WB[4], nullptr, nullptr, QKVS, 512, 0, 24, 384, WeP2, G);
    k_gs_kv<false><<<gkv, 64, 0, stream>>>(Hb, WB[4], QKVS);
    k_conv<<<gconv, 256, 0, stream>>>(rowstart, rec, QKVS, WeP2, G, Ha);        // H3 = Ha
    // MLP2: Tb = gelu(Ha@M2a+b2a); Hb = gelu(Tb@M2b+b2b) + Ha  (= H4)
    k_gs<false, 8, false, true, false, false><<<gm, 64, 0, stream>>>(
        Ha, WB[10], b2a, nullptr, Tb, 128, 0, 0, 0, nullptr, nullptr);
    k_gs<false, 8, false, true, true, false><<<gm, 64, 0, stream>>>(
        Tb, WB[11], b2b, Ha, Hb, 128, 0, 0, 0, nullptr, nullptr);

    // ----- final MLP: Tb = gelu(Hb@Wf1+bf1); out = gelu(Tb@Wf2+bf2) fp32 -----
    k_gs<false, 8, false, true, false, false><<<gm, 64, 0, stream>>>(
        Hb, WB[12], bf1, nullptr, Tb, 128, 0, 0, 0, nullptr, nullptr);
    k_gs<false, 4, false, true, false, true><<<gm, 64, 0, stream>>>(
        Tb, WB[13], bf2, nullptr, d_out, 64, 0, 0, 0, nullptr, nullptr);
}

// Round 15
// 437.147 us; speedup vs baseline: 1.0503x; 1.0503x over previous
//
#include <hip/hip_runtime.h>
#include <hip/hip_bf16.h>
#include <math.h>

// Problem constants (fixed by the reference)
#define NN 50000
#define NE 800000
#define NPAD 50048   // 782 * 64 — tail-free GEMM tiles
#define NB_SCAN 196  // ceil(NN/256)

typedef unsigned short u16;
typedef unsigned int u32;
typedef __attribute__((ext_vector_type(8))) short short8;   // 8 bf16 (MFMA A/B frag)
typedef __attribute__((ext_vector_type(4))) float float4v;  // MFMA C/D frag

__device__ __forceinline__ float us2f(u16 u) { return __uint_as_float(((unsigned)u) << 16); }
__device__ __forceinline__ float blo(u32 u) { return __uint_as_float(u << 16); }
__device__ __forceinline__ float bhi(u32 u) { return __uint_as_float(u & 0xffff0000u); }
__device__ __forceinline__ u16 f2us(float f) {   // fp32 -> bf16 RNE
    unsigned x = __float_as_uint(f);
    return (u16)((x + 0x7FFFu + ((x >> 16) & 1u)) >> 16);
}
// tanh-gelu via sigmoid identity: 0.5*(1+tanh(u)) = sigmoid(2u)
__device__ __forceinline__ float gelu_f(float x) {
    float p = x * x;
    float t = x * fmaf(p, 0.0713548162726f, 1.5957691216057308f);  // 2u
    float e = __expf(-t);
    return x * __builtin_amdgcn_rcpf(1.0f + e);
}
// intra-wave LDS ordering fence (for wave-private staging buffers)
__device__ __forceinline__ void lds_fence() {
    asm volatile("s_waitcnt lgkmcnt(0)" ::: "memory");
}

// ---- MFMA with B-frags served from LDS section buffer ----
// secbuf layout: tile t (0..7) at t*2048 u16; frag q at +q*512; lane l at +l*8.
__device__ __forceinline__ float4v mfma4l(const u16* sec, int t, int l,
                                          short8 a0, short8 a1, short8 a2, short8 a3) {
    const short8* wp = (const short8*)(sec + t * 2048) + l;
    short8 b0 = wp[0], b1 = wp[64], b2 = wp[128], b3 = wp[192];
    float4v acc = {0.f, 0.f, 0.f, 0.f};
    acc = __builtin_amdgcn_mfma_f32_16x16x32_bf16(a0, b0, acc, 0, 0, 0);
    acc = __builtin_amdgcn_mfma_f32_16x16x32_bf16(a1, b1, acc, 0, 0, 0);
    acc = __builtin_amdgcn_mfma_f32_16x16x32_bf16(a2, b2, acc, 0, 0, 0);
    acc = __builtin_amdgcn_mfma_f32_16x16x32_bf16(a3, b3, acc, 0, 0, 0);
    return acc;
}

// cooperative section load: 32KB = 8 tiles = 16384 u16. s0 -> tiles 0..3
// (secbuf[0..8191]), s1 -> tiles 4..7 (secbuf[8192..16383]). 4 waves x 8 x 1KB.
__device__ __forceinline__ void load_sec32(const u16* __restrict__ s0,
                                           const u16* __restrict__ s1,
                                           u16* secbuf, int w, int l) {
    const u16* base = (w < 2) ? s0 : s1;
    int off = (w & 1) * 8;
    int dbase = (w < 2) ? 0 : 8192;   // u16 elements (bug in R14: was 16384)
#pragma unroll
    for (int j = 0; j < 8; ++j) {
        int ch = off + j;
        uint4 v = *(const uint4*)(base + ch * 512 + l * 8);
        *(uint4*)(secbuf + dbase + ch * 512 + l * 8) = v;
    }
}
// 16KB (4 tiles = 8192 u16) variant
__device__ __forceinline__ void load_sec16(const u16* __restrict__ s0,
                                           u16* secbuf, int w, int l) {
#pragma unroll
    for (int j = 0; j < 4; ++j) {
        int ch = w * 4 + j;
        uint4 v = *(const uint4*)(s0 + ch * 512 + l * 8);
        *(uint4*)(secbuf + ch * 512 + l * 8) = v;
    }
}

// ---------------- CSR build ----------------

__global__ void k_hist(const int* __restrict__ dstv, int* __restrict__ deg) {
    int e = blockIdx.x * blockDim.x + threadIdx.x;
    if (e < NE) atomicAdd(&deg[dstv[e]], 1);
}

__global__ __launch_bounds__(256) void k_scan1(const int* __restrict__ deg,
                                               int* __restrict__ rowstart,
                                               int* __restrict__ bsum) {
    __shared__ int wtot[4];
    int i = blockIdx.x * 256 + threadIdx.x;
    int lane = threadIdx.x & 63, w = threadIdx.x >> 6;
    int v = (i < NN) ? deg[i] : 0;
    int incl = v;
#pragma unroll
    for (int d = 1; d < 64; d <<= 1) {
        int tv = __shfl_up(incl, d);
        if (lane >= d) incl += tv;
    }
    if (lane == 63) wtot[w] = incl;
    __syncthreads();
    if (threadIdx.x == 0) {
        int s = 0;
#pragma unroll
        for (int j = 0; j < 4; ++j) { int t = wtot[j]; wtot[j] = s; s += t; }
        bsum[blockIdx.x] = s;
    }
    __syncthreads();
    if (i < NN) rowstart[i] = incl - v + wtot[w];
}

__global__ __launch_bounds__(256) void k_scan2(int* __restrict__ bsum) {
    __shared__ int wtot[4];
    int t = threadIdx.x;
    int lane = t & 63, w = t >> 6;
    int v = (t < NB_SCAN) ? bsum[t] : 0;
    int incl = v;
#pragma unroll
    for (int d = 1; d < 64; d <<= 1) {
        int tv = __shfl_up(incl, d);
        if (lane >= d) incl += tv;
    }
    if (lane == 63) wtot[w] = incl;
    __syncthreads();
    if (t == 0) {
        int s = 0;
#pragma unroll
        for (int j = 0; j < 4; ++j) { int tt = wtot[j]; wtot[j] = s; s += tt; }
    }
    __syncthreads();
    if (t < NB_SCAN) bsum[t] = incl - v + wtot[w];
}

__global__ void k_scan3(const int* __restrict__ bsum, int* __restrict__ rowstart,
                        int* __restrict__ cursor) {
    int i = blockIdx.x * 256 + threadIdx.x;
    if (i < NN) {
        int v = rowstart[i] + bsum[blockIdx.x];
        rowstart[i] = v;
        cursor[i] = v;
    }
    if (i == 0) rowstart[NN] = NE;
}

__global__ void k_scatter(const int* __restrict__ srcv, const int* __restrict__ dstv,
                          const float* __restrict__ eattr, int* __restrict__ cursor,
                          int4* __restrict__ rec) {
    int e = blockIdx.x * blockDim.x + threadIdx.x;
    if (e >= NE) return;
    int dst = dstv[e];
    int pos = atomicAdd(&cursor[dst], 1);
    int4 r;
    r.x = srcv[e];
    r.y = __float_as_int(eattr[e * 3 + 0]);
    r.z = __float_as_int(eattr[e * 3 + 1]);
    r.w = __float_as_int(eattr[e * 3 + 2]);
    rec[pos] = r;
}

// ---------------- weight fp32 -> bf16, permuted into B-frag order ----------------
// WP u16 layout: tile*2048 + q*512 + l*8 + j <=> W[tile*16+(l&15)][q*32+(l>>4)*8+j]

struct CvtEnt { const float* s; u16* d; int n; };
struct CvtTab { CvtEnt e[14]; };
__global__ void k_cvt_w(CvtTab tab) {
    CvtEnt E = tab.e[blockIdx.x >> 3];
    int chunk = blockIdx.x & 7;
    int per = E.n >> 3;
    int lo = chunk * per, hi = lo + per;
    for (int o = lo + threadIdx.x; o < hi; o += blockDim.x) {
        int tile = o >> 11;
        int q = (o >> 9) & 3;
        int l = (o >> 3) & 63;
        int j = o & 7;
        int row = tile * 16 + (l & 15);
        int col = q * 32 + (l >> 4) * 8 + j;
        E.d[o] = f2us(E.s[row * 128 + col]);
    }
}

// padded We tables: WeP[c] = {We[c][0], We[c][1], We[c][2], 0}
__global__ void k_prep_we(const float* __restrict__ We1, const float* __restrict__ We2,
                          float4* __restrict__ WeP1, float4* __restrict__ WeP2) {
    int t = threadIdx.x;
    if (t < 128) {
        WeP1[t] = make_float4(We1[t * 3], We1[t * 3 + 1], We1[t * 3 + 2], 0.f);
    } else {
        int c = t - 128;
        WeP2[c] = make_float4(We2[c * 3], We2[c * 3 + 1], We2[c * 3 + 2], 0.f);
    }
}

// =============== GEMM-chain kernels: LDS-shared B sections ===============
// Block = 4 waves = 64 rows; per section: cooperative 32KB B stage -> barrier ->
// all waves consume via ds_read -> barrier -> next section. Wave-private C staging.

__device__ __forceinline__ void stage_plain(u16* buf, int kb, int m, int tt, float4v acc) {
#pragma unroll
    for (int r = 0; r < 4; ++r) buf[(kb * 4 + r) * 136 + tt * 16 + m] = f2us(acc[r]);
}
__device__ __forceinline__ void store128(const u16* buf, u16* dst, int r0w, int coff, int l) {
#pragma unroll
    for (int it = 0; it < 4; ++it) {
        int j = it * 64 + l;
        int row = j >> 4, col = (j & 15) * 8;
        *(uint4*)(dst + (size_t)(r0w + row) * 512 + coff + col) = *(const uint4*)&buf[row * 136 + col];
    }
}
__device__ __forceinline__ void read_frags(const u16* buf, int m, int kb,
                                           short8& f0, short8& f1, short8& f2, short8& f3) {
    const u16* p = buf + m * 136 + kb * 8;
    f0 = *(const short8*)(p);
    f1 = *(const short8*)(p + 32);
    f2 = *(const short8*)(p + 64);
    f3 = *(const short8*)(p + 96);
}

// g precompute: q tile (16x128 bf16, plain layout) in buf; lane l computes
// g[row=m][head=kb][j] = sum_d q[row][kb*32+d] * WeP[kb*32+d].j
__device__ __forceinline__ void compute_g(const u16* buf, const float4* __restrict__ WeP,
                                          float4* __restrict__ G, int r0w, int m, int kb) {
    const u16* qr = buf + m * 136 + kb * 32;
    const float4* wp = WeP + kb * 32;
    float g0 = 0.f, g1 = 0.f, g2 = 0.f;
#pragma unroll
    for (int b = 0; b < 4; ++b) {
        short8 qv = *(const short8*)(qr + b * 8);
        const u16* qq = (const u16*)&qv;
#pragma unroll
        for (int d = 0; d < 8; ++d) {
            float qvf = us2f(qq[d]);
            float4 wv = wp[b * 8 + d];
            g0 = fmaf(qvf, wv.x, g0);
            g1 = fmaf(qvf, wv.y, g1);
            g2 = fmaf(qvf, wv.z, g2);
        }
    }
    G[(size_t)(r0w + m) * 4 + kb] = make_float4(g0, g1, g2, 0.f);
}

// kv staging: col c -> k at (c>>2)*8+(c&3), v at (c>>2)*8+4+(c&3)
// i.e. groups {k[4p..4p+3], v[4p..4p+3]} — conv lane li reads 32B at 128+li*16.

// ---------------- layer-1 QKVS GEMM (A = fp32 x) ----------------

__global__ __launch_bounds__(256) void k_qkvs1(const float* __restrict__ Ain,
                                               const u16* __restrict__ W,
                                               const float4* __restrict__ WeP,
                                               float4* __restrict__ G,
                                               u16* __restrict__ QKVS) {
    __shared__ u16 secbuf[8 * 2048];
    __shared__ u16 myb[4][16 * 136];
    int tid = threadIdx.x;
    int l = tid & 63, w = tid >> 6, m = l & 15, kb = l >> 4;
    int r0w = blockIdx.x * 64 + w * 16;
    u16* my = myb[w];

    short8 a0, a1, a2, a3;
    {
        const float* ap = Ain + (size_t)(r0w + m) * 128;
        bool ok = (r0w + m) < NN;
        short8* dsts[4] = {&a0, &a1, &a2, &a3};
#pragma unroll
        for (int i = 0; i < 4; ++i) {
            short8 r;
            if (ok) {
                const float* p = ap + (kb + i * 4) * 8;
                float4 f0 = *(const float4*)p;
                float4 f1 = *(const float4*)(p + 4);
                r[0]=(short)f2us(f0.x); r[1]=(short)f2us(f0.y); r[2]=(short)f2us(f0.z); r[3]=(short)f2us(f0.w);
                r[4]=(short)f2us(f1.x); r[5]=(short)f2us(f1.y); r[6]=(short)f2us(f1.z); r[7]=(short)f2us(f1.w);
            } else {
#pragma unroll
                for (int j = 0; j < 8; ++j) r[j] = 0;
            }
            *dsts[i] = r;
        }
    }

    // ---- section q: tiles 0..7 (+ g precompute) ----
    load_sec32(W, W + 8192, secbuf, w, l);
    __syncthreads();
#pragma unroll
    for (int tt = 0; tt < 8; ++tt) stage_plain(my, kb, m, tt, mfma4l(secbuf, tt, l, a0, a1, a2, a3));
    lds_fence();
    store128(my, QKVS, r0w, 0, l);
    compute_g(my, WeP, G, r0w, m, kb);
    __syncthreads();
    // ---- section kv-lo: k tiles 8..11 (sec 0..3) + v tiles 16..19 (sec 4..7) ----
    load_sec32(W + 8 * 2048, W + 16 * 2048, secbuf, w, l);
    __syncthreads();
#pragma unroll
    for (int tt = 0; tt < 4; ++tt) {
        float4v acc = mfma4l(secbuf, tt, l, a0, a1, a2, a3);
        int c = tt * 32 + 8 * (m >> 2) + (m & 3);
#pragma unroll
        for (int r = 0; r < 4; ++r) my[(kb * 4 + r) * 136 + c] = f2us(acc[r]);
    }
#pragma unroll
    for (int tt = 0; tt < 4; ++tt) {
        float4v acc = mfma4l(secbuf, 4 + tt, l, a0, a1, a2, a3);
        int c = tt * 32 + 8 * (m >> 2) + (m & 3) + 4;
#pragma unroll
        for (int r = 0; r < 4; ++r) my[(kb * 4 + r) * 136 + c] = f2us(acc[r]);
    }
    lds_fence();
    store128(my, QKVS, r0w, 128, l);
    __syncthreads();
    // ---- section kv-hi: k 12..15 + v 20..23 ----
    load_sec32(W + 12 * 2048, W + 20 * 2048, secbuf, w, l);
    __syncthreads();
#pragma unroll
    for (int tt = 0; tt < 4; ++tt) {
        float4v acc = mfma4l(secbuf, tt, l, a0, a1, a2, a3);
        int c = tt * 32 + 8 * (m >> 2) + (m & 3);
#pragma unroll
        for (int r = 0; r < 4; ++r) my[(kb * 4 + r) * 136 + c] = f2us(acc[r]);
    }
#pragma unroll
    for (int tt = 0; tt < 4; ++tt) {
        float4v acc = mfma4l(secbuf, 4 + tt, l, a0, a1, a2, a3);
        int c = tt * 32 + 8 * (m >> 2) + (m & 3) + 4;
#pragma unroll
        for (int r = 0; r < 4; ++r) my[(kb * 4 + r) * 136 + c] = f2us(acc[r]);
    }
    lds_fence();
    store128(my, QKVS, r0w, 256, l);
    __syncthreads();
    // ---- section s: tiles 24..31 ----
    load_sec32(W + 24 * 2048, W + 28 * 2048, secbuf, w, l);
    __syncthreads();
#pragma unroll
    for (int tt = 0; tt < 8; ++tt) stage_plain(my, kb, m, tt, mfma4l(secbuf, tt, l, a0, a1, a2, a3));
    lds_fence();
    store128(my, QKVS, r0w, 384, l);
}

// ---------------- fused MLP + next-layer QKVS ----------------

__global__ __launch_bounds__(256) void k_mlp_qkvs(const u16* __restrict__ Ain,
                                                  const u16* __restrict__ Wm,
                                                  const float* __restrict__ bias1,
                                                  const float* __restrict__ bias2,
                                                  const u16* __restrict__ Wq,
                                                  const float4* __restrict__ WeP,
                                                  float4* __restrict__ G,
                                                  u16* __restrict__ QKVS) {
    __shared__ u16 secbuf[8 * 2048];
    __shared__ u16 shb[4][16 * 136];
    __shared__ u16 t1b[4][16 * 136];
    int tid = threadIdx.x;
    int l = tid & 63, w = tid >> 6, m = l & 15, kb = l >> 4;
    int r0w = blockIdx.x * 64 + w * 16;
    u16* sh = shb[w];
    u16* t1 = t1b[w];

    const short8* arow = (const short8*)(Ain + (size_t)(r0w + m) * 128);
    short8 a0 = arow[kb], a1 = arow[kb + 4], a2 = arow[kb + 8], a3 = arow[kb + 12];
    {   // stage A (residual source), linear rows
        u16* p = sh + m * 136 + kb * 8;
        *(short8*)(p) = a0;
        *(short8*)(p + 32) = a1;
        *(short8*)(p + 64) = a2;
        *(short8*)(p + 96) = a3;
    }
    // ---- GEMM1 (M1a) -> t1 gelu ----
    load_sec32(Wm, Wm + 8192, secbuf, w, l);
    __syncthreads();
#pragma unroll
    for (int tt = 0; tt < 8; ++tt) {
        float4v acc = mfma4l(secbuf, tt, l, a0, a1, a2, a3);
        float bv = bias1[tt * 16 + m];
#pragma unroll
        for (int r = 0; r < 4; ++r)
            t1[(kb * 4 + r) * 136 + tt * 16 + m] = f2us(gelu_f(acc[r] + bv));
    }
    lds_fence();
    short8 c0, c1, c2, c3;
    read_frags(t1, m, kb, c0, c1, c2, c3);
    __syncthreads();
    // ---- GEMM2 (M1b) + residual -> sh = H2 ----
    load_sec32(Wm + 16384, Wm + 16384 + 8192, secbuf, w, l);
    __syncthreads();
#pragma unroll
    for (int tt = 0; tt < 8; ++tt) {
        float4v acc = mfma4l(secbuf, tt, l, c0, c1, c2, c3);
        float bv = bias2[tt * 16 + m];
#pragma unroll
        for (int r = 0; r < 4; ++r) {
            int idx = (kb * 4 + r) * 136 + tt * 16 + m;
            sh[idx] = f2us(gelu_f(acc[r] + bv) + us2f(sh[idx]));
        }
    }
    lds_fence();
    short8 h0, h1, h2, h3;
    read_frags(sh, m, kb, h0, h1, h2, h3);
    __syncthreads();
    // ---- q section (Wq tiles 0..7) + g ----
    load_sec32(Wq, Wq + 8192, secbuf, w, l);
    __syncthreads();
#pragma unroll
    for (int tt = 0; tt < 8; ++tt) stage_plain(t1, kb, m, tt, mfma4l(secbuf, tt, l, h0, h1, h2, h3));
    lds_fence();
    store128(t1, QKVS, r0w, 0, l);
    compute_g(t1, WeP, G, r0w, m, kb);
    __syncthreads();
    // ---- kv-lo ----
    load_sec32(Wq + 8 * 2048, Wq + 16 * 2048, secbuf, w, l);
    __syncthreads();
#pragma unroll
    for (int tt = 0; tt < 4; ++tt) {
        float4v acc = mfma4l(secbuf, tt, l, h0, h1, h2, h3);
        int c = tt * 32 + 8 * (m >> 2) + (m & 3);
#pragma unroll
        for (int r = 0; r < 4; ++r) t1[(kb * 4 + r) * 136 + c] = f2us(acc[r]);
    }
#pragma unroll
    for (int tt = 0; tt < 4; ++tt) {
        float4v acc = mfma4l(secbuf, 4 + tt, l, h0, h1, h2, h3);
        int c = tt * 32 + 8 * (m >> 2) + (m & 3) + 4;
#pragma unroll
        for (int r = 0; r < 4; ++r) t1[(kb * 4 + r) * 136 + c] = f2us(acc[r]);
    }
    lds_fence();
    store128(t1, QKVS, r0w, 128, l);
    __syncthreads();
    // ---- kv-hi ----
    load_sec32(Wq + 12 * 2048, Wq + 20 * 2048, secbuf, w, l);
    __syncthreads();
#pragma unroll
    for (int tt = 0; tt < 4; ++tt) {
        float4v acc = mfma4l(secbuf, tt, l, h0, h1, h2, h3);
        int c = tt * 32 + 8 * (m >> 2) + (m & 3);
#pragma unroll
        for (int r = 0; r < 4; ++r) t1[(kb * 4 + r) * 136 + c] = f2us(acc[r]);
    }
#pragma unroll
    for (int tt = 0; tt < 4; ++tt) {
        float4v acc = mfma4l(secbuf, 4 + tt, l, h0, h1, h2, h3);
        int c = tt * 32 + 8 * (m >> 2) + (m & 3) + 4;
#pragma unroll
        for (int r = 0; r < 4; ++r) t1[(kb * 4 + r) * 136 + c] = f2us(acc[r]);
    }
    lds_fence();
    store128(t1, QKVS, r0w, 256, l);
    __syncthreads();
    // ---- s section ----
    load_sec32(Wq + 24 * 2048, Wq + 28 * 2048, secbuf, w, l);
    __syncthreads();
#pragma unroll
    for (int tt = 0; tt < 8; ++tt) stage_plain(t1, kb, m, tt, mfma4l(secbuf, tt, l, h0, h1, h2, h3));
    lds_fence();
    store128(t1, QKVS, r0w, 384, l);
}

// ---------------- fused MLP + final MLP ----------------

__global__ __launch_bounds__(256) void k_mlp_final(const u16* __restrict__ Ain,
                                                   const u16* __restrict__ Wm,
                                                   const float* __restrict__ bias1,
                                                   const float* __restrict__ bias2,
                                                   const u16* __restrict__ Wf,
                                                   const float* __restrict__ bf1,
                                                   const float* __restrict__ bf2,
                                                   float* __restrict__ outp) {
    __shared__ u16 secbuf[8 * 2048];
    __shared__ u16 shb[4][16 * 136];
    __shared__ u16 t1b[4][16 * 136];
    int tid = threadIdx.x;
    int l = tid & 63, w = tid >> 6, m = l & 15, kb = l >> 4;
    int r0w = blockIdx.x * 64 + w * 16;
    u16* sh = shb[w];
    u16* t1 = t1b[w];

    const short8* arow = (const short8*)(Ain + (size_t)(r0w + m) * 128);
    short8 a0 = arow[kb], a1 = arow[kb + 4], a2 = arow[kb + 8], a3 = arow[kb + 12];
    {
        u16* p = sh + m * 136 + kb * 8;
        *(short8*)(p) = a0;
        *(short8*)(p + 32) = a1;
        *(short8*)(p + 64) = a2;
        *(short8*)(p + 96) = a3;
    }
    // ---- GEMM1 (M2a) ----
    load_sec32(Wm, Wm + 8192, secbuf, w, l);
    __syncthreads();
#pragma unroll
    for (int tt = 0; tt < 8; ++tt) {
        float4v acc = mfma4l(secbuf, tt, l, a0, a1, a2, a3);
        float bv = bias1[tt * 16 + m];
#pragma unroll
        for (int r = 0; r < 4; ++r)
            t1[(kb * 4 + r) * 136 + tt * 16 + m] = f2us(gelu_f(acc[r] + bv));
    }
    lds_fence();
    short8 c0, c1, c2, c3;
    read_frags(t1, m, kb, c0, c1, c2, c3);
    __syncthreads();
    // ---- GEMM2 (M2b) + residual -> sh = H4 ----
    load_sec32(Wm + 16384, Wm + 16384 + 8192, secbuf, w, l);
    __syncthreads();
#pragma unroll
    for (int tt = 0; tt < 8; ++tt) {
        float4v acc = mfma4l(secbuf, tt, l, c0, c1, c2, c3);
        float bv = bias2[tt * 16 + m];
#pragma unroll
        for (int r = 0; r < 4; ++r) {
            int idx = (kb * 4 + r) * 136 + tt * 16 + m;
            sh[idx] = f2us(gelu_f(acc[r] + bv) + us2f(sh[idx]));
        }
    }
    lds_fence();
    short8 h0, h1, h2, h3;
    read_frags(sh, m, kb, h0, h1, h2, h3);
    __syncthreads();
    // ---- G3 = gelu(H4@Wf1+bf1) -> t1 ----
    load_sec32(Wf, Wf + 8192, secbuf, w, l);
    __syncthreads();
#pragma unroll
    for (int tt = 0; tt < 8; ++tt) {
        float4v acc = mfma4l(secbuf, tt, l, h0, h1, h2, h3);
        float bv = bf1[tt * 16 + m];
#pragma unroll
        for (int r = 0; r < 4; ++r)
            t1[(kb * 4 + r) * 136 + tt * 16 + m] = f2us(gelu_f(acc[r] + bv));
    }
    lds_fence();
    short8 f0, f1, f2, f3;
    read_frags(t1, m, kb, f0, f1, f2, f3);
    __syncthreads();
    // ---- G4 = gelu(G3@Wf2+bf2), 4 tiles -> t1, fp32 store ----
    load_sec16(Wf + 16384, secbuf, w, l);
    __syncthreads();
#pragma unroll
    for (int tt = 0; tt < 4; ++tt) {
        float4v acc = mfma4l(secbuf, tt, l, f0, f1, f2, f3);
        float bv = bf2[tt * 16 + m];
#pragma unroll
        for (int r = 0; r < 4; ++r)
            t1[(kb * 4 + r) * 136 + tt * 16 + m] = f2us(gelu_f(acc[r] + bv));
    }
    lds_fence();
#pragma unroll
    for (int it = 0; it < 2; ++it) {
        int j = it * 64 + l;
        int row = j >> 3, col = (j & 7) * 8;
        int grow = r0w + row;
        if (grow < NN) {
            uint4 pk = *(const uint4*)&t1[row * 136 + col];
            const u16* pv = (const u16*)&pk;
            float* po = outp + (size_t)grow * 64 + col;
            float4 o0 = {us2f(pv[0]), us2f(pv[1]), us2f(pv[2]), us2f(pv[3])};
            float4 o1 = {us2f(pv[4]), us2f(pv[5]), us2f(pv[6]), us2f(pv[7])};
            *(float4*)po = o0;
            *(float4*)(po + 4) = o1;
        }
    }
}

// ---------------- TransformerConv: 4 edges/wave, 8 cols/lane, pipelined gather ----------------

__global__ __launch_bounds__(256) void k_conv(const int* __restrict__ rowstart,
                                              const int4* __restrict__ rec,
                                              const u16* __restrict__ qkvs,
                                              const float4* __restrict__ WeP,
                                              const float4* __restrict__ G,
                                              u16* __restrict__ out) {
    int n = blockIdx.x * 4 + (threadIdx.x >> 6);
    int l = threadIdx.x & 63;
    int quarter = l >> 4;
    int li = l & 15;
    int c0 = li * 8;
    const u16* qrow = qkvs + (size_t)n * 512;
    uint4 qu = *(const uint4*)(qrow + c0);
    const float SC = 0.17677669529663687f;
    float q0 = blo(qu.x) * SC, q1 = bhi(qu.x) * SC, q2 = blo(qu.y) * SC, q3 = bhi(qu.y) * SC;
    float q4 = blo(qu.z) * SC, q5 = bhi(qu.z) * SC, q6 = blo(qu.w) * SC, q7 = bhi(qu.w) * SC;
    float4 gg = G[(size_t)n * 4 + (li >> 2)];
    float g0 = gg.x * SC, g1 = gg.y * SC, g2 = gg.z * SC;

    int e0 = rowstart[n], e1 = rowstart[n + 1];
    int deg = e1 - e0;
    float ss = 0.f, S0 = 0.f, S1 = 0.f, S2 = 0.f;
    float o0 = 0.f, o1 = 0.f, o2 = 0.f, o3 = 0.f, o4 = 0.f, o5 = 0.f, o6 = 0.f, o7 = 0.f;

    if (deg > 0) {
        int iters = (deg + 3) >> 2;
        int eb = e0 + quarter;
        int elast = e1 - 1;
        int4 r0 = rec[min(eb, elast)];
        int4 r1 = rec[min(eb + 4, elast)];
        const u16* kvB = qkvs + 128 + (size_t)li * 16;
        uint4 kA = *(const uint4*)(kvB + (size_t)r0.x * 512);
        uint4 kB = *(const uint4*)(kvB + (size_t)r0.x * 512 + 8);
        for (int i = 0; i < iters; ++i) {
            int4 r2 = rec[min(eb + 4 * (i + 2), elast)];
            const u16* kp = kvB + (size_t)r1.x * 512;
            uint4 nA = *(const uint4*)(kp);
            uint4 nB = *(const uint4*)(kp + 8);
            float part = q0 * blo(kA.x) + q1 * bhi(kA.x) + q2 * blo(kA.y) + q3 * bhi(kA.y)
                       + q4 * blo(kB.x) + q5 * bhi(kB.x) + q6 * blo(kB.y) + q7 * bhi(kB.y);
            part += __shfl_xor(part, 1);
            part += __shfl_xor(part, 2);
            float ea0 = __int_as_float(r0.y), ea1 = __int_as_float(r0.z), ea2 = __int_as_float(r0.w);
            float alpha = fmaf(ea2, g2, fmaf(ea1, g1, fmaf(ea0, g0, part)));
            float p = __expf(fminf(alpha, 80.f));
            p = (eb + 4 * i < e1) ? p : 0.f;
            o0 = fmaf(p, blo(kA.z), o0);
            o1 = fmaf(p, bhi(kA.z), o1);
            o2 = fmaf(p, blo(kA.w), o2);
            o3 = fmaf(p, bhi(kA.w), o3);
            o4 = fmaf(p, blo(kB.z), o4);
            o5 = fmaf(p, bhi(kB.z), o5);
            o6 = fmaf(p, blo(kB.w), o6);
            o7 = fmaf(p, bhi(kB.w), o7);
            ss += p;
            S0 = fmaf(p, ea0, S0);
            S1 = fmaf(p, ea1, S1);
            S2 = fmaf(p, ea2, S2);
            r0 = r1; r1 = r2; kA = nA; kB = nB;
        }
    }
    o0 += __shfl_xor(o0, 16); o1 += __shfl_xor(o1, 16); o2 += __shfl_xor(o2, 16); o3 += __shfl_xor(o3, 16);
    o4 += __shfl_xor(o4, 16); o5 += __shfl_xor(o5, 16); o6 += __shfl_xor(o6, 16); o7 += __shfl_xor(o7, 16);
    ss += __shfl_xor(ss, 16); S0 += __shfl_xor(S0, 16); S1 += __shfl_xor(S1, 16); S2 += __shfl_xor(S2, 16);
    o0 += __shfl_xor(o0, 32); o1 += __shfl_xor(o1, 32); o2 += __shfl_xor(o2, 32); o3 += __shfl_xor(o3, 32);
    o4 += __shfl_xor(o4, 32); o5 += __shfl_xor(o5, 32); o6 += __shfl_xor(o6, 32); o7 += __shfl_xor(o7, 32);
    ss += __shfl_xor(ss, 32); S0 += __shfl_xor(S0, 32); S1 += __shfl_xor(S1, 32); S2 += __shfl_xor(S2, 32);

    if (quarter == 0) {
        float inv = __builtin_amdgcn_rcpf(fmaxf(ss, 1e-16f));
        float4 w0 = WeP[c0 + 0], w1 = WeP[c0 + 1], w2 = WeP[c0 + 2], w3 = WeP[c0 + 3];
        float4 w4 = WeP[c0 + 4], w5 = WeP[c0 + 5], w6 = WeP[c0 + 6], w7 = WeP[c0 + 7];
        o0 += w0.x * S0 + w0.y * S1 + w0.z * S2;
        o1 += w1.x * S0 + w1.y * S1 + w1.z * S2;
        o2 += w2.x * S0 + w2.y * S1 + w2.z * S2;
        o3 += w3.x * S0 + w3.y * S1 + w3.z * S2;
        o4 += w4.x * S0 + w4.y * S1 + w4.z * S2;
        o5 += w5.x * S0 + w5.y * S1 + w5.z * S2;
        o6 += w6.x * S0 + w6.y * S1 + w6.z * S2;
        o7 += w7.x * S0 + w7.y * S1 + w7.z * S2;
        uint4 su = *(const uint4*)(qrow + 384 + c0);
        float r0v = fmaf(o0, inv, blo(su.x));
        float r1v = fmaf(o1, inv, bhi(su.x));
        float r2v = fmaf(o2, inv, blo(su.y));
        float r3v = fmaf(o3, inv, bhi(su.y));
        float r4v = fmaf(o4, inv, blo(su.z));
        float r5v = fmaf(o5, inv, bhi(su.z));
        float r6v = fmaf(o6, inv, blo(su.w));
        float r7v = fmaf(o7, inv, bhi(su.w));
        uint4 ou;
        ou.x = (u32)f2us(r0v) | ((u32)f2us(r1v) << 16);
        ou.y = (u32)f2us(r2v) | ((u32)f2us(r3v) << 16);
        ou.z = (u32)f2us(r4v) | ((u32)f2us(r5v) << 16);
        ou.w = (u32)f2us(r6v) | ((u32)f2us(r7v) << 16);
        *(uint4*)(out + (size_t)n * 128 + c0) = ou;
    }
}

// ---------------- launcher ----------------

extern "C" void kernel_launch(void* const* d_in, const int* in_sizes, int n_in,
                              void* d_out, int out_size, void* d_ws, size_t ws_size,
                              hipStream_t stream) {
    const float* x = (const float*)d_in[0];
    const int* ei = (const int*)d_in[1];
    const float* eattr = (const float*)d_in[2];
    const float* Wq1 = (const float*)d_in[3];
    const float* Wk1 = (const float*)d_in[4];
    const float* Wv1 = (const float*)d_in[5];
    const float* We1 = (const float*)d_in[6];
    const float* Ws1 = (const float*)d_in[7];
    const float* M1a = (const float*)d_in[8];
    const float* b1a = (const float*)d_in[9];
    const float* M1b = (const float*)d_in[10];
    const float* b1b = (const float*)d_in[11];
    const float* Wq2 = (const float*)d_in[12];
    const float* Wk2 = (const float*)d_in[13];
    const float* Wv2 = (const float*)d_in[14];
    const float* We2 = (const float*)d_in[15];
    const float* Ws2 = (const float*)d_in[16];
    const float* M2a = (const float*)d_in[17];
    const float* b2a = (const float*)d_in[18];
    const float* M2b = (const float*)d_in[19];
    const float* b2b = (const float*)d_in[20];
    const float* Wf1 = (const float*)d_in[21];
    const float* bf1 = (const float*)d_in[22];
    const float* Wf2 = (const float*)d_in[23];
    const float* bf2 = (const float*)d_in[24];

    char* ws = (char*)d_ws;
    size_t off = 0;
    auto alloc = [&](size_t bytes) -> void* {
        void* p = ws + off;
        off = (off + bytes + 255) & ~(size_t)255;
        return p;
    };
    int* deg = (int*)alloc((size_t)NN * 4);
    int* rowstart = (int*)alloc((size_t)(NN + 1) * 4);
    int* cursor = (int*)alloc((size_t)NN * 4);
    int* bsum = (int*)alloc((size_t)NB_SCAN * 4);
    int4* rec = (int4*)alloc((size_t)NE * 16);
    u16* QKVS = (u16*)alloc((size_t)NPAD * 512 * 2);
    u16* Ha = (u16*)alloc((size_t)NPAD * 128 * 2);
    float4* G = (float4*)alloc((size_t)NPAD * 4 * 16);
    float4* WeP1 = (float4*)alloc(128 * 16);
    float4* WeP2 = (float4*)alloc(128 * 16);
    // weight order: [Wq1 Wk1 Wv1 Ws1][Wq2 Wk2 Wv2 Ws2][M1a M1b][M2a M2b][Wf1 Wf2]
    u16* WB[14];
    const int wsz[14] = {16384, 16384, 16384, 16384, 16384, 16384, 16384,
                         16384, 16384, 16384, 16384, 16384, 16384, 8192};
    for (int i = 0; i < 14; ++i) WB[i] = (u16*)alloc((size_t)wsz[i] * 2);

    const int* srcv = ei;
    const int* dstv = ei + NE;

    // CSR build
    hipMemsetAsync(deg, 0, (size_t)NN * 4, stream);
    k_hist<<<(NE + 255) / 256, 256, 0, stream>>>(dstv, deg);
    k_scan1<<<NB_SCAN, 256, 0, stream>>>(deg, rowstart, bsum);
    k_scan2<<<1, 256, 0, stream>>>(bsum);
    k_scan3<<<NB_SCAN, 256, 0, stream>>>(bsum, rowstart, cursor);
    k_scatter<<<(NE + 255) / 256, 256, 0, stream>>>(srcv, dstv, eattr, cursor, rec);

    CvtTab tab;
    const float* wsrc[14] = {Wq1, Wk1, Wv1, Ws1, Wq2, Wk2, Wv2, Ws2,
                             M1a, M1b, M2a, M2b, Wf1, Wf2};
    for (int i = 0; i < 14; ++i) { tab.e[i].s = wsrc[i]; tab.e[i].d = WB[i]; tab.e[i].n = wsz[i]; }
    k_cvt_w<<<112, 256, 0, stream>>>(tab);
    k_prep_we<<<1, 256, 0, stream>>>(We1, We2, WeP1, WeP2);

    dim3 grd(NPAD / 64);   // 782
    dim3 gconv(NN / 4);    // 12500

    // layer 1
    k_qkvs1<<<grd, 256, 0, stream>>>(x, WB[0], WeP1, G, QKVS);
    k_conv<<<gconv, 256, 0, stream>>>(rowstart, rec, QKVS, WeP1, G, Ha);        // H1 = Ha
    // MLP1 + layer-2 QKVS (H2 never hits HBM); also g for conv2
    k_mlp_qkvs<<<grd, 256, 0, stream>>>(Ha, WB[8], b1a, b1b, WB[4], WeP2, G, QKVS);
    k_conv<<<gconv, 256, 0, stream>>>(rowstart, rec, QKVS, WeP2, G, Ha);        // H3 = Ha
    // MLP2 + final MLP (H4 never hits HBM)
    k_mlp_final<<<grd, 256, 0, stream>>>(Ha, WB[10], b2a, b2b, WB[12], bf1, bf2, (float*)d_out);
}